// Round 1
// baseline (101.093 us; speedup 1.0000x reference)
//
#include <hip/hip_runtime.h>

// Fused upfirdn2d: up2(FIR12, H) -> up2(FIR12, W) -> +bias -> lrelu*sqrt2
//                  -> down2(FIR12, H) -> down2(FIR12, W)
// x: (32,128,64,64) f32.  One block per (n,c) slice; whole slice pipeline in LDS.
//
// Derived index math (verified against lax.conv_general_dilated semantics):
//   z[i][c]  = sum_{j == i (mod 2)} (2*fu[j]) * x[(i-j)/2][c],  (i-j)/2 in [0,63]
//   y[i][w]  = sum_{j == w (mod 2)} (2*fu[j]) * z[i][(w-j)/2]   then lrelu(y+b)*g
//   wb[o][w] = sum_{j=0..11} fd[j] * y[2o+11-j][w]
//   out[o][p]= sum_{j=0..11} fd[j] * wb[o][2p+11-j]

#define NTHREADS 1024
#define SLOPE 0.2f
#define GAIN 1.41421356237309504880f

// LDS float offsets
#define XB_OFF 0          // 64*64   = 4096 floats, stride 64
#define ZB_OFF 4096       // 138*64  = 8832 floats, stride 64
#define WB_OFF 0          // 64*140  = 8960 floats, stride 140 (aliases xb+zb)
#define YB_OFF 12928      // 138*140 = 19320 floats, stride 140 (pad->16B row align)
#define LDS_FLOATS (12928 + 19320)

__global__ __launch_bounds__(NTHREADS) void fused_upfirdn_lrelu(
    const float* __restrict__ x,
    const float* __restrict__ bias,
    const float* __restrict__ upf,
    const float* __restrict__ dnf,
    float* __restrict__ out)
{
    extern __shared__ float lds[];
    float* xb = lds + XB_OFF;
    float* zb = lds + ZB_OFF;
    float* wb = lds + WB_OFF;
    float* yb = lds + YB_OFF;

    const int t = threadIdx.x;
    const int s = blockIdx.x;       // n*128 + c
    const int c = s & 127;

    // 12-tap filters -> (uniform) registers. fu pre-scaled by UP=2.
    float fu[12], fd[12];
#pragma unroll
    for (int j = 0; j < 12; ++j) { fu[j] = 2.0f * upf[j]; fd[j] = dnf[j]; }
    const float bv = bias[c];

    const float* xg = x + (size_t)s * 4096;
    float* og = out + (size_t)s * 4096;

    // ---- A: stage x slice (64x64) into LDS, one float4 per thread ----
    {
        const float4 v = reinterpret_cast<const float4*>(xg)[t];
        reinterpret_cast<float4*>(xb)[t] = v;
    }
    __syncthreads();

    // ---- B: up-H -> z[138][64].  Rows 2m,2m+1 share x rows m-5..m. ----
    for (int task = t; task < 69 * 16; task += NTHREADS) {
        const int m  = task >> 4;           // 0..68
        const int c4 = (task & 15) << 2;    // 0..60
        float a0[4] = {0.f, 0.f, 0.f, 0.f};
        float a1[4] = {0.f, 0.f, 0.f, 0.f};
#pragma unroll
        for (int tt = 0; tt < 6; ++tt) {
            const int r = m - tt;
            if (r >= 0 && r <= 63) {
                const float4 xv = *reinterpret_cast<const float4*>(xb + r * 64 + c4);
                const float w0 = fu[2 * tt], w1 = fu[2 * tt + 1];
                a0[0] += w0 * xv.x; a0[1] += w0 * xv.y; a0[2] += w0 * xv.z; a0[3] += w0 * xv.w;
                a1[0] += w1 * xv.x; a1[1] += w1 * xv.y; a1[2] += w1 * xv.z; a1[3] += w1 * xv.w;
            }
        }
        *reinterpret_cast<float4*>(zb + (2 * m)     * 64 + c4) = make_float4(a0[0], a0[1], a0[2], a0[3]);
        *reinterpret_cast<float4*>(zb + (2 * m + 1) * 64 + c4) = make_float4(a1[0], a1[1], a1[2], a1[3]);
    }
    __syncthreads();

    // ---- C: up-W + bias + lrelu -> y[138][140(pad)] ----
    // task -> (row i, column-block m4); m4 covers m = 4*m4 .. 4*m4+3 (m valid to 68)
    for (int task = t; task < 138 * 18; task += NTHREADS) {
        const int i = task / 18;
        const int m4 = task - i * 18;
        const int mbase = m4 << 2;
        const float* zr = zb + i * 64;

        float zv[12];   // z cols [mbase-8, mbase+4), zero outside [0,63]
#pragma unroll
        for (int q = 0; q < 3; ++q) {
            const int cb = mbase - 8 + (q << 2);
            if (cb >= 0 && cb + 3 <= 63) {
                const float4 v = *reinterpret_cast<const float4*>(zr + cb);
                zv[4 * q] = v.x; zv[4 * q + 1] = v.y; zv[4 * q + 2] = v.z; zv[4 * q + 3] = v.w;
            } else {
#pragma unroll
                for (int e = 0; e < 4; ++e) {
                    const int cc = cb + e;
                    zv[4 * q + e] = (cc >= 0 && cc <= 63) ? zr[cc] : 0.0f;
                }
            }
        }

        float yv[8];
#pragma unroll
        for (int e = 0; e < 4; ++e) {       // m = mbase+e ; outputs w = 2m, 2m+1
            float a0 = 0.0f, a1 = 0.0f;
#pragma unroll
            for (int tt = 0; tt < 6; ++tt) {
                const float zz = zv[8 + e - tt];
                a0 += fu[2 * tt]     * zz;
                a1 += fu[2 * tt + 1] * zz;
            }
            a0 += bv; a1 += bv;
            a0 = (a0 >= 0.0f ? a0 : SLOPE * a0) * GAIN;
            a1 = (a1 >= 0.0f ? a1 : SLOPE * a1) * GAIN;
            yv[2 * e] = a0; yv[2 * e + 1] = a1;
        }
        float* yr = yb + i * 140 + (mbase << 1);
        if (m4 < 17) {
            *reinterpret_cast<float4*>(yr)     = make_float4(yv[0], yv[1], yv[2], yv[3]);
            *reinterpret_cast<float4*>(yr + 4) = make_float4(yv[4], yv[5], yv[6], yv[7]);
        } else {            // m4 == 17 -> only w=136,137 are real
            yr[0] = yv[0]; yr[1] = yv[1];
        }
    }
    __syncthreads();

    // ---- D: down-H -> wb[64][140] (aliases xb/zb; x,z dead now) ----
    // task -> (o2, col4): computes rows o=2*o2, 2*o2+1 from y rows 4*o2 .. 4*o2+13
    for (int task = t; task < 32 * 35; task += NTHREADS) {
        const int o2 = task / 35;
        const int col4 = (task - o2 * 35) << 2;   // 0..136
        const int rbase = o2 << 2;
        float a0[4] = {0.f, 0.f, 0.f, 0.f};
        float a1[4] = {0.f, 0.f, 0.f, 0.f};
#pragma unroll
        for (int q = 0; q < 14; ++q) {
            const float4 v = *reinterpret_cast<const float4*>(yb + (rbase + q) * 140 + col4);
            if (q <= 11) {
                const float w = fd[11 - q];
                a0[0] += w * v.x; a0[1] += w * v.y; a0[2] += w * v.z; a0[3] += w * v.w;
            }
            if (q >= 2) {
                const float w = fd[13 - q];
                a1[0] += w * v.x; a1[1] += w * v.y; a1[2] += w * v.z; a1[3] += w * v.w;
            }
        }
        *reinterpret_cast<float4*>(wb + (2 * o2)     * 140 + col4) = make_float4(a0[0], a0[1], a0[2], a0[3]);
        *reinterpret_cast<float4*>(wb + (2 * o2 + 1) * 140 + col4) = make_float4(a1[0], a1[1], a1[2], a1[3]);
    }
    __syncthreads();

    // ---- E: down-W -> out, one float4 of outputs per task ----
    for (int task = t; task < 64 * 16; task += NTHREADS) {
        const int o = task >> 4;
        const int ow4 = task & 15;
        const float* wr = wb + o * 140 + (ow4 << 3);
        float wv[20];
#pragma unroll
        for (int q = 0; q < 5; ++q) {
            const float4 v = *reinterpret_cast<const float4*>(wr + (q << 2));
            wv[4 * q] = v.x; wv[4 * q + 1] = v.y; wv[4 * q + 2] = v.z; wv[4 * q + 3] = v.w;
        }
        float rv[4];
#pragma unroll
        for (int e = 0; e < 4; ++e) {
            float a = 0.0f;
#pragma unroll
            for (int j = 0; j < 12; ++j) a += fd[j] * wv[2 * e + 11 - j];
            rv[e] = a;
        }
        *reinterpret_cast<float4*>(og + o * 64 + (ow4 << 2)) = make_float4(rv[0], rv[1], rv[2], rv[3]);
    }
}

extern "C" void kernel_launch(void* const* d_in, const int* in_sizes, int n_in,
                              void* d_out, int out_size, void* d_ws, size_t ws_size,
                              hipStream_t stream) {
    const float* x    = (const float*)d_in[0];
    const float* bias = (const float*)d_in[1];
    const float* upf  = (const float*)d_in[2];
    const float* dnf  = (const float*)d_in[3];
    float* out = (float*)d_out;

    const int n_slices = 32 * 128;              // 4096 blocks, one per (n,c)
    const size_t lds_bytes = (size_t)LDS_FLOATS * sizeof(float);
    hipLaunchKernelGGL(fused_upfirdn_lrelu, dim3(n_slices), dim3(NTHREADS),
                       lds_bytes, stream, x, bias, upf, dnf, out);
}

// Round 2
// 90.169 us; speedup vs baseline: 1.1211x; 1.1211x over previous
//
#include <hip/hip_runtime.h>

// Fused upfirdn2d: up2(FIR12,H) -> up2(FIR12,W) -> +bias -> lrelu*sqrt2
//                  -> down2(FIR12,H) -> down2(FIR12,W)
// x: (32,128,64,64) f32.
// R1: split each slice into two half-slices (32 out rows) -> 79KB LDS,
//     2 blocks/CU; branchless phases via zero-padded halos in LDS.
//
// Index math:
//   z[i][c]  = sum_{j == i (mod 2)} (2*fu[j]) * x[(i-j)/2][c]
//   y[i][w]  = sum_{j == w (mod 2)} (2*fu[j]) * z[i][(w-j)/2]; lrelu(y+b)*g
//   wb[o][w] = sum_{j} fd[j] * y[2o+11-j][w]
//   out[o][p]= sum_{j} fd[j] * wb[o][2p+11-j]

#define NT 1024
#define SLOPE 0.2f
#define GAIN 1.41421356237309504880f

// Half-slice geometry: block handles out rows [o0, o0+32), o0 = 0 or 32.
// Needs y/z rows [2*o0, 2*o0+74) and x rows [o0-5, o0+36] (zero outside [0,63]).
#define XROWS 42
#define XSTRIDE 68            // 68 mod 32 = 4 -> no bank wrap alias
#define ZROWS 74
#define ZSTRIDE 84            // 8 left pad + 64 + 8 right pad + 4 (84 mod 32 = 20)
#define ZPAD 8
#define YROWS 74
#define YSTRIDE 144           // 138 cols + 6 slack -> unconditional float4x2 writes
#define WSTRIDE 140           // 140 mod 32 = 12

#define XB_OFF 0
#define ZB_OFF (XROWS * XSTRIDE)              // 2856
#define WB_OFF 0                              // aliases xb+zb (dead by then)
#define YB_OFF (ZB_OFF + ZROWS * ZSTRIDE)     // 9072
#define LDS_FLOATS (YB_OFF + YROWS * YSTRIDE) // 19728 floats = 78912 B -> 2 blk/CU

__global__ __launch_bounds__(NT, 8) void fused_upfirdn_lrelu(
    const float* __restrict__ x,
    const float* __restrict__ bias,
    const float* __restrict__ upf,
    const float* __restrict__ dnf,
    float* __restrict__ out)
{
    extern __shared__ float lds[];
    float* xb = lds + XB_OFF;
    float* zb = lds + ZB_OFF;
    float* wb = lds + WB_OFF;
    float* yb = lds + YB_OFF;

    const int t = threadIdx.x;
    const int bid = blockIdx.x;
    const int s = bid >> 1;           // slice = n*128 + c
    const int o0 = (bid & 1) << 5;    // 0 or 32
    const int c = s & 127;
    const int xlo = o0 - 5;

    float fu[12], fd[12];
#pragma unroll
    for (int j = 0; j < 12; ++j) { fu[j] = 2.0f * upf[j]; fd[j] = dnf[j]; }
    const float bv = bias[c];

    const float* xg = x + (size_t)s * 4096;
    float* og = out + (size_t)s * 4096;

    // ---- A: stage x rows [xlo, xlo+42) (zero-filled halo) + zero z pads ----
    for (int task = t; task < XROWS * 16; task += NT) {      // 672
        const int rl = task >> 4;
        const int c4 = (task & 15) << 2;
        const int r = xlo + rl;
        float4 v = make_float4(0.f, 0.f, 0.f, 0.f);
        if (r >= 0 && r <= 63) v = *reinterpret_cast<const float4*>(xg + r * 64 + c4);
        *reinterpret_cast<float4*>(xb + rl * XSTRIDE + c4) = v;
    }
    for (int task = t; task < ZROWS * 5; task += NT) {       // 370
        const int rl = task / 5;
        const int p = task - rl * 5;
        const int col = (p < 2) ? (p << 2) : (72 + ((p - 2) << 2));
        *reinterpret_cast<float4*>(zb + rl * ZSTRIDE + col) = make_float4(0.f, 0.f, 0.f, 0.f);
    }
    __syncthreads();

    // ---- B: up-H -> z local rows [0,74), cols at ZPAD+ (branchless) ----
    for (int task = t; task < 37 * 16; task += NT) {         // 592
        const int ml = task >> 4;                            // 0..36
        const int c4 = (task & 15) << 2;
        const float* xr = xb + (ml + 5) * XSTRIDE + c4;      // rows ml+5-tt
        float a0[4] = {0.f,0.f,0.f,0.f}, a1[4] = {0.f,0.f,0.f,0.f};
#pragma unroll
        for (int tt = 0; tt < 6; ++tt) {
            const float4 xv = *reinterpret_cast<const float4*>(xr - tt * XSTRIDE);
            const float w0 = fu[2 * tt], w1 = fu[2 * tt + 1];
            a0[0] += w0 * xv.x; a0[1] += w0 * xv.y; a0[2] += w0 * xv.z; a0[3] += w0 * xv.w;
            a1[0] += w1 * xv.x; a1[1] += w1 * xv.y; a1[2] += w1 * xv.z; a1[3] += w1 * xv.w;
        }
        float* zr0 = zb + (2 * ml) * ZSTRIDE + ZPAD + c4;
        *reinterpret_cast<float4*>(zr0)           = make_float4(a0[0], a0[1], a0[2], a0[3]);
        *reinterpret_cast<float4*>(zr0 + ZSTRIDE) = make_float4(a1[0], a1[1], a1[2], a1[3]);
    }
    __syncthreads();

    // ---- C: up-W + bias + lrelu -> y[74][144] (fully branchless) ----
    for (int task = t; task < YROWS * 18; task += NT) {      // 1332
        const int il = task / 18;
        const int m4 = task - il * 18;
        const int mbase = m4 << 2;
        // local col mbase corresponds to real z col mbase-8 (pads are zero)
        const float* zr = zb + il * ZSTRIDE + mbase;
        float zv[12];
#pragma unroll
        for (int q = 0; q < 3; ++q) {
            const float4 v = *reinterpret_cast<const float4*>(zr + (q << 2));
            zv[4 * q] = v.x; zv[4 * q + 1] = v.y; zv[4 * q + 2] = v.z; zv[4 * q + 3] = v.w;
        }
        float yv[8];
#pragma unroll
        for (int e = 0; e < 4; ++e) {            // m = mbase+e -> w = 2m, 2m+1
            float a0 = 0.0f, a1 = 0.0f;
#pragma unroll
            for (int tt = 0; tt < 6; ++tt) {
                const float zz = zv[8 + e - tt];
                a0 += fu[2 * tt]     * zz;
                a1 += fu[2 * tt + 1] * zz;
            }
            a0 += bv; a1 += bv;
            a0 = (a0 >= 0.0f ? a0 : SLOPE * a0) * GAIN;
            a1 = (a1 >= 0.0f ? a1 : SLOPE * a1) * GAIN;
            yv[2 * e] = a0; yv[2 * e + 1] = a1;
        }
        float* yr = yb + il * YSTRIDE + (mbase << 1);
        *reinterpret_cast<float4*>(yr)     = make_float4(yv[0], yv[1], yv[2], yv[3]);
        *reinterpret_cast<float4*>(yr + 4) = make_float4(yv[4], yv[5], yv[6], yv[7]);
    }
    __syncthreads();

    // ---- D: down-H -> wb[32][140] (aliases xb/zb) ----
    for (int task = t; task < 16 * 35; task += NT) {         // 560
        const int o2 = task / 35;                            // 0..15
        const int col4 = (task - o2 * 35) << 2;              // 0..136
        const int rbase = o2 << 2;
        float a0[4] = {0.f,0.f,0.f,0.f}, a1[4] = {0.f,0.f,0.f,0.f};
#pragma unroll
        for (int q = 0; q < 14; ++q) {
            const float4 v = *reinterpret_cast<const float4*>(yb + (rbase + q) * YSTRIDE + col4);
            if (q <= 11) {
                const float w = fd[11 - q];
                a0[0] += w * v.x; a0[1] += w * v.y; a0[2] += w * v.z; a0[3] += w * v.w;
            }
            if (q >= 2) {
                const float w = fd[13 - q];
                a1[0] += w * v.x; a1[1] += w * v.y; a1[2] += w * v.z; a1[3] += w * v.w;
            }
        }
        float* wr0 = wb + (2 * o2) * WSTRIDE + col4;
        *reinterpret_cast<float4*>(wr0)           = make_float4(a0[0], a0[1], a0[2], a0[3]);
        *reinterpret_cast<float4*>(wr0 + WSTRIDE) = make_float4(a1[0], a1[1], a1[2], a1[3]);
    }
    __syncthreads();

    // ---- E: down-W -> out rows [o0, o0+32) ----
    for (int task = t; task < 32 * 16; task += NT) {         // 512
        const int ol = task >> 4;                            // 0..31
        const int ow4 = task & 15;
        const float* wr = wb + ol * WSTRIDE + (ow4 << 3);
        float wv[20];
#pragma unroll
        for (int q = 0; q < 5; ++q) {
            const float4 v = *reinterpret_cast<const float4*>(wr + (q << 2));
            wv[4 * q] = v.x; wv[4 * q + 1] = v.y; wv[4 * q + 2] = v.z; wv[4 * q + 3] = v.w;
        }
        float rv[4];
#pragma unroll
        for (int e = 0; e < 4; ++e) {
            float a = 0.0f;
#pragma unroll
            for (int j = 0; j < 12; ++j) a += fd[j] * wv[2 * e + 11 - j];
            rv[e] = a;
        }
        *reinterpret_cast<float4*>(og + (o0 + ol) * 64 + (ow4 << 2)) =
            make_float4(rv[0], rv[1], rv[2], rv[3]);
    }
}

extern "C" void kernel_launch(void* const* d_in, const int* in_sizes, int n_in,
                              void* d_out, int out_size, void* d_ws, size_t ws_size,
                              hipStream_t stream) {
    const float* x    = (const float*)d_in[0];
    const float* bias = (const float*)d_in[1];
    const float* upf  = (const float*)d_in[2];
    const float* dnf  = (const float*)d_in[3];
    float* out = (float*)d_out;

    const int n_blocks = 32 * 128 * 2;   // two half-slices per (n,c)
    const size_t lds_bytes = (size_t)LDS_FLOATS * sizeof(float);
    hipLaunchKernelGGL(fused_upfirdn_lrelu, dim3(n_blocks), dim3(NT),
                       lds_bytes, stream, x, bias, upf, dnf, out);
}

// Round 3
// 85.617 us; speedup vs baseline: 1.1808x; 1.0532x over previous
//
#include <hip/hip_runtime.h>

// Fused upfirdn2d: up2(FIR12,H) -> up2(FIR12,W) -> +bias -> lrelu*sqrt2
//                  -> down2(FIR12,H) -> down2(FIR12,W)
// x: (32,128,64,64) f32.  Two half-slice blocks per (n,c); pipeline in LDS.
// R2: LDS-pipe is the bottleneck -> fewer/wider LDS ops per phase + bank fixes.
//
// Index math:
//   z[i][c]  = sum_{j == i (mod 2)} (2*fu[j]) * x[(i-j)/2][c]
//   y[i][w]  = sum_{j == w (mod 2)} (2*fu[j]) * z[i][(w-j)/2]; lrelu(y+b)*g
//   wb[o][w] = sum_{j} fd[j] * y[2o+11-j][w]
//   out[o][p]= sum_{j} fd[j] * wb[o][2p+11-j]

#define NT 1024
#define SLOPE 0.2f
#define GAIN 1.41421356237309504880f

#define XROWS 43              // x rows [o0-5, o0+37]; row 42 only read, maybe junk-guarded
#define XSTRIDE 68            // 68 mod 32 = 4
#define ZROWS 74
#define ZSTRIDE 84            // 84 mod 32 = 20; 8 left pad + 64 + 12 right pad
#define ZPAD 8
#define YROWS 74
#define YSTRIDE 148           // 148 mod 32 = 20  (144 was ==16 -> 2x write conflicts)
#define WSTRIDE 140           // 140 mod 32 = 12

#define XB_OFF 0
#define ZB_OFF (XROWS * XSTRIDE)              // 2924
#define WB_OFF 0                              // aliases xb+zb (dead by phase D)
#define YB_OFF (ZB_OFF + ZROWS * ZSTRIDE)     // 9140
#define LDS_FLOATS (YB_OFF + YROWS * YSTRIDE) // 20092 floats = 80368 B  (<= 80 KiB/blk)

__global__ __launch_bounds__(NT, 8) void fused_upfirdn_lrelu(
    const float* __restrict__ x,
    const float* __restrict__ bias,
    const float* __restrict__ upf,
    const float* __restrict__ dnf,
    float* __restrict__ out)
{
    extern __shared__ float lds[];
    float* xb = lds + XB_OFF;
    float* zb = lds + ZB_OFF;
    float* wb = lds + WB_OFF;
    float* yb = lds + YB_OFF;

    const int t = threadIdx.x;
    const int bid = blockIdx.x;
    const int s = bid >> 1;           // slice = n*128 + c
    const int o0 = (bid & 1) << 5;    // 0 or 32
    const int c = s & 127;
    const int xlo = o0 - 5;

    // uniform loads -> SGPRs (R2: VGPR=24/SGPR=48 confirmed)
    float fu[12], fd[12];
#pragma unroll
    for (int j = 0; j < 12; ++j) { fu[j] = 2.0f * upf[j]; fd[j] = dnf[j]; }
    const float bv = bias[c];

    const float* xg = x + (size_t)s * 4096;
    float* og = out + (size_t)s * 4096;

    // ---- A: stage x rows [xlo, xlo+43) (zero halo) + zero z pads ----
    for (int task = t; task < XROWS * 16; task += NT) {      // 688
        const int rl = task >> 4;
        const int c4 = (task & 15) << 2;
        const int r = xlo + rl;
        float4 v = make_float4(0.f, 0.f, 0.f, 0.f);
        if (r >= 0 && r <= 63) v = *reinterpret_cast<const float4*>(xg + r * 64 + c4);
        *reinterpret_cast<float4*>(xb + rl * XSTRIDE + c4) = v;
    }
    for (int task = t; task < ZROWS * 5; task += NT) {       // 370
        const int rl = task / 5;
        const int p = task - rl * 5;
        const int col = (p < 2) ? (p << 2) : (72 + ((p - 2) << 2));
        *reinterpret_cast<float4*>(zb + rl * ZSTRIDE + col) = make_float4(0.f, 0.f, 0.f, 0.f);
    }
    __syncthreads();

    // ---- B: up-H -> z rows [0,74).  Task = (k, c4): m = 2k, 2k+1 share 7 x rows ----
    for (int task = t; task < 19 * 16; task += NT) {         // 304
        const int k = task >> 4;                             // 0..18
        const int c4 = (task & 15) << 2;
        const float* xr = xb + (2 * k) * XSTRIDE + c4;       // x local rows 2k..2k+6
        float4 xv[7];
#pragma unroll
        for (int r = 0; r < 7; ++r) xv[r] = *reinterpret_cast<const float4*>(xr + r * XSTRIDE);
        float a0[4] = {0,0,0,0}, a1[4] = {0,0,0,0}, b0[4] = {0,0,0,0}, b1[4] = {0,0,0,0};
#pragma unroll
        for (int d = 0; d < 6; ++d) {        // m=2k uses xv[0..5], tt = 5-d
            const float w0 = fu[2 * (5 - d)], w1 = fu[2 * (5 - d) + 1];
            a0[0] += w0 * xv[d].x; a0[1] += w0 * xv[d].y; a0[2] += w0 * xv[d].z; a0[3] += w0 * xv[d].w;
            a1[0] += w1 * xv[d].x; a1[1] += w1 * xv[d].y; a1[2] += w1 * xv[d].z; a1[3] += w1 * xv[d].w;
        }
#pragma unroll
        for (int d = 1; d < 7; ++d) {        // m=2k+1 uses xv[1..6], tt = 6-d
            const float w0 = fu[2 * (6 - d)], w1 = fu[2 * (6 - d) + 1];
            b0[0] += w0 * xv[d].x; b0[1] += w0 * xv[d].y; b0[2] += w0 * xv[d].z; b0[3] += w0 * xv[d].w;
            b1[0] += w1 * xv[d].x; b1[1] += w1 * xv[d].y; b1[2] += w1 * xv[d].z; b1[3] += w1 * xv[d].w;
        }
        float* zr = zb + (4 * k) * ZSTRIDE + ZPAD + c4;
        *reinterpret_cast<float4*>(zr)               = make_float4(a0[0], a0[1], a0[2], a0[3]);
        *reinterpret_cast<float4*>(zr + ZSTRIDE)     = make_float4(a1[0], a1[1], a1[2], a1[3]);
        if (k < 18) {
            *reinterpret_cast<float4*>(zr + 2 * ZSTRIDE) = make_float4(b0[0], b0[1], b0[2], b0[3]);
            *reinterpret_cast<float4*>(zr + 3 * ZSTRIDE) = make_float4(b1[0], b1[1], b1[2], b1[3]);
        }
    }
    __syncthreads();

    // ---- C: up-W + bias + lrelu -> y[74][148].  Task = (il, m8): 8 m's, 16 outputs ----
    for (int task = t; task < YROWS * 9; task += NT) {       // 666
        const int il = task / 9;
        const int m8 = task - il * 9;
        const int mbase = m8 << 3;
        const float* zr = zb + il * ZSTRIDE + mbase;         // local col mbase = real col mbase-8
        float zv[16];
#pragma unroll
        for (int q = 0; q < 4; ++q) {
            const float4 v = *reinterpret_cast<const float4*>(zr + (q << 2));
            zv[4 * q] = v.x; zv[4 * q + 1] = v.y; zv[4 * q + 2] = v.z; zv[4 * q + 3] = v.w;
        }
        float yv[16];
#pragma unroll
        for (int e = 0; e < 8; ++e) {        // m = mbase+e -> w = 2m, 2m+1
            float a0 = 0.0f, a1 = 0.0f;
#pragma unroll
            for (int tt = 0; tt < 6; ++tt) {
                const float zz = zv[8 + e - tt];
                a0 += fu[2 * tt]     * zz;
                a1 += fu[2 * tt + 1] * zz;
            }
            a0 += bv; a1 += bv;
            a0 = (a0 >= 0.0f ? a0 : SLOPE * a0) * GAIN;
            a1 = (a1 >= 0.0f ? a1 : SLOPE * a1) * GAIN;
            yv[2 * e] = a0; yv[2 * e + 1] = a1;
        }
        float* yr = yb + il * YSTRIDE + (mbase << 1);
#pragma unroll
        for (int q = 0; q < 4; ++q)
            *reinterpret_cast<float4*>(yr + (q << 2)) =
                make_float4(yv[4 * q], yv[4 * q + 1], yv[4 * q + 2], yv[4 * q + 3]);
    }
    __syncthreads();

    // ---- D: down-H -> wb[32][140].  Task = (og, cc): 4 out rows from 18 y rows ----
    for (int task = t; task < 8 * 35; task += NT) {          // 280
        const int og = task / 35;                            // 0..7
        const int col4 = (task - og * 35) << 2;              // 0..136
        const float* yr = yb + (og << 3) * YSTRIDE + col4;   // y rows 8og .. 8og+17
        float acc[4][4] = {{0,0,0,0},{0,0,0,0},{0,0,0,0},{0,0,0,0}};
#pragma unroll
        for (int r = 0; r < 18; ++r) {
            const float4 v = *reinterpret_cast<const float4*>(yr + r * YSTRIDE);
#pragma unroll
            for (int e = 0; e < 4; ++e) {
                if (r >= 2 * e && r <= 2 * e + 11) {         // compile-time per (r,e)
                    const float w = fd[11 - r + 2 * e];
                    acc[e][0] += w * v.x; acc[e][1] += w * v.y;
                    acc[e][2] += w * v.z; acc[e][3] += w * v.w;
                }
            }
        }
        float* wr = wb + (og << 2) * WSTRIDE + col4;
#pragma unroll
        for (int e = 0; e < 4; ++e)
            *reinterpret_cast<float4*>(wr + e * WSTRIDE) =
                make_float4(acc[e][0], acc[e][1], acc[e][2], acc[e][3]);
    }
    __syncthreads();

    // ---- E: down-W -> out.  Task = (ol, ow8): 8 outputs from 28 wb floats ----
    for (int task = t; task < 32 * 8; task += NT) {          // 256
        const int ol = task >> 3;                            // 0..31
        const int ow8 = task & 7;
        const float* wr = wb + ol * WSTRIDE + (ow8 << 4);
        float wv[28];
#pragma unroll
        for (int q = 0; q < 7; ++q) {
            const float4 v = *reinterpret_cast<const float4*>(wr + (q << 2));
            wv[4 * q] = v.x; wv[4 * q + 1] = v.y; wv[4 * q + 2] = v.z; wv[4 * q + 3] = v.w;
        }
        float rv[8];
#pragma unroll
        for (int e = 0; e < 8; ++e) {
            float a = 0.0f;
#pragma unroll
            for (int j = 0; j < 12; ++j) a += fd[j] * wv[2 * e + 11 - j];
            rv[e] = a;
        }
        float* orow = og + (o0 + ol) * 64 + (ow8 << 3);
        *reinterpret_cast<float4*>(orow)     = make_float4(rv[0], rv[1], rv[2], rv[3]);
        *reinterpret_cast<float4*>(orow + 4) = make_float4(rv[4], rv[5], rv[6], rv[7]);
    }
}

extern "C" void kernel_launch(void* const* d_in, const int* in_sizes, int n_in,
                              void* d_out, int out_size, void* d_ws, size_t ws_size,
                              hipStream_t stream) {
    const float* x    = (const float*)d_in[0];
    const float* bias = (const float*)d_in[1];
    const float* upf  = (const float*)d_in[2];
    const float* dnf  = (const float*)d_in[3];
    float* out = (float*)d_out;

    const int n_blocks = 32 * 128 * 2;   // two half-slices per (n,c)
    const size_t lds_bytes = (size_t)LDS_FLOATS * sizeof(float);
    hipLaunchKernelGGL(fused_upfirdn_lrelu, dim3(n_blocks), dim3(NT),
                       lds_bytes, stream, x, bias, upf, dnf, out);
}

// Round 4
// 76.194 us; speedup vs baseline: 1.3268x; 1.1237x over previous
//
#include <hip/hip_runtime.h>

// Fused upfirdn2d: up2(FIR12,H) -> up2(FIR12,W) -> +bias -> lrelu*sqrt2
//                  -> down2(FIR12,H) -> down2(FIR12,W)
// x: (32,128,64,64) f32.  Two half-slice blocks per (n,c); pipeline in LDS.
// R3: bank-conflict fix via lane->task remap: consecutive lanes walk ROWS
//     (row strides 84/148/140 floats are 80B/80B/48B mod 128B -> full 32-bank
//     rotation for b128 groups-of-8), instead of columns (32B/64B strides
//     that hit 16/8 banks -> 2-way/4-way conflicts).
//
// Index math:
//   z[i][c]  = sum_{j == i (mod 2)} (2*fu[j]) * x[(i-j)/2][c]
//   y[i][w]  = sum_{j == w (mod 2)} (2*fu[j]) * z[i][(w-j)/2]; lrelu(y+b)*g
//   wb[o][w] = sum_{j} fd[j] * y[2o+11-j][w]
//   out[o][p]= sum_{j} fd[j] * wb[o][2p+11-j]

#define NT 1024
#define SLOPE 0.2f
#define GAIN 1.41421356237309504880f

#define XROWS 43
#define XSTRIDE 68            // 16B lane-stride phases use col-walk: 68%32=4 ok
#define ZROWS 74
#define ZSTRIDE 84            // 84*4B = 336B ; 336%128 = 80B -> full rotation row-walk
#define ZPAD 8
#define YROWS 74
#define YSTRIDE 148           // 148*4B = 592B ; 592%128 = 80B -> full rotation row-walk
#define WSTRIDE 140           // 140*4B = 560B ; 560%128 = 48B -> full rotation row-walk

#define XB_OFF 0
#define ZB_OFF (XROWS * XSTRIDE)              // 2924
#define WB_OFF 0                              // aliases xb+zb (dead by phase D)
#define YB_OFF (ZB_OFF + ZROWS * ZSTRIDE)     // 9140
#define LDS_FLOATS (YB_OFF + YROWS * YSTRIDE) // 20092 floats = 80368 B

__global__ __launch_bounds__(NT, 8) void fused_upfirdn_lrelu(
    const float* __restrict__ x,
    const float* __restrict__ bias,
    const float* __restrict__ upf,
    const float* __restrict__ dnf,
    float* __restrict__ out)
{
    extern __shared__ float lds[];
    float* xb = lds + XB_OFF;
    float* zb = lds + ZB_OFF;
    float* wb = lds + WB_OFF;
    float* yb = lds + YB_OFF;

    const int t = threadIdx.x;
    const int bid = blockIdx.x;
    const int s = bid >> 1;           // slice = n*128 + c
    const int o0 = (bid & 1) << 5;    // 0 or 32
    const int c = s & 127;
    const int xlo = o0 - 5;

    float fu[12], fd[12];
#pragma unroll
    for (int j = 0; j < 12; ++j) { fu[j] = 2.0f * upf[j]; fd[j] = dnf[j]; }
    const float bv = bias[c];

    const float* xg = x + (size_t)s * 4096;
    float* og = out + (size_t)s * 4096;

    // ---- A: stage x rows [xlo, xlo+43) (zero halo) + zero z pads ----
    for (int task = t; task < XROWS * 16; task += NT) {      // 688, 16B lane-stride: clean
        const int rl = task >> 4;
        const int c4 = (task & 15) << 2;
        const int r = xlo + rl;
        float4 v = make_float4(0.f, 0.f, 0.f, 0.f);
        if (r >= 0 && r <= 63) v = *reinterpret_cast<const float4*>(xg + r * 64 + c4);
        *reinterpret_cast<float4*>(xb + rl * XSTRIDE + c4) = v;
    }
    for (int task = t; task < ZROWS * 5; task += NT) {       // 370
        const int rl = task / 5;
        const int p = task - rl * 5;
        const int col = (p < 2) ? (p << 2) : (72 + ((p - 2) << 2));
        *reinterpret_cast<float4*>(zb + rl * ZSTRIDE + col) = make_float4(0.f, 0.f, 0.f, 0.f);
    }
    __syncthreads();

    // ---- B: up-H -> z rows [0,74).  Task = (k, c4); 16B lane-stride: clean ----
    for (int task = t; task < 19 * 16; task += NT) {         // 304
        const int k = task >> 4;                             // 0..18
        const int c4 = (task & 15) << 2;
        const float* xr = xb + (2 * k) * XSTRIDE + c4;       // x local rows 2k..2k+6
        float4 xv[7];
#pragma unroll
        for (int r = 0; r < 7; ++r) xv[r] = *reinterpret_cast<const float4*>(xr + r * XSTRIDE);
        float a0[4] = {0,0,0,0}, a1[4] = {0,0,0,0}, b0[4] = {0,0,0,0}, b1[4] = {0,0,0,0};
#pragma unroll
        for (int d = 0; d < 6; ++d) {        // m=2k uses xv[0..5], tt = 5-d
            const float w0 = fu[2 * (5 - d)], w1 = fu[2 * (5 - d) + 1];
            a0[0] += w0 * xv[d].x; a0[1] += w0 * xv[d].y; a0[2] += w0 * xv[d].z; a0[3] += w0 * xv[d].w;
            a1[0] += w1 * xv[d].x; a1[1] += w1 * xv[d].y; a1[2] += w1 * xv[d].z; a1[3] += w1 * xv[d].w;
        }
#pragma unroll
        for (int d = 1; d < 7; ++d) {        // m=2k+1 uses xv[1..6], tt = 6-d
            const float w0 = fu[2 * (6 - d)], w1 = fu[2 * (6 - d) + 1];
            b0[0] += w0 * xv[d].x; b0[1] += w0 * xv[d].y; b0[2] += w0 * xv[d].z; b0[3] += w0 * xv[d].w;
            b1[0] += w1 * xv[d].x; b1[1] += w1 * xv[d].y; b1[2] += w1 * xv[d].z; b1[3] += w1 * xv[d].w;
        }
        float* zr = zb + (4 * k) * ZSTRIDE + ZPAD + c4;
        *reinterpret_cast<float4*>(zr)               = make_float4(a0[0], a0[1], a0[2], a0[3]);
        *reinterpret_cast<float4*>(zr + ZSTRIDE)     = make_float4(a1[0], a1[1], a1[2], a1[3]);
        if (k < 18) {
            *reinterpret_cast<float4*>(zr + 2 * ZSTRIDE) = make_float4(b0[0], b0[1], b0[2], b0[3]);
            *reinterpret_cast<float4*>(zr + 3 * ZSTRIDE) = make_float4(b1[0], b1[1], b1[2], b1[3]);
        }
    }
    __syncthreads();

    // ---- C: up-W + bias + lrelu -> y[74][148].
    //      Task = (m8, il) with il FAST-varying: consecutive lanes -> consecutive
    //      rows -> 80B effective stride -> conflict-free reads AND writes. ----
    for (int task = t; task < 9 * YROWS; task += NT) {       // 666
        const int m8 = task / YROWS;
        const int il = task - m8 * YROWS;
        const int mbase = m8 << 3;
        const float* zr = zb + il * ZSTRIDE + mbase;         // local col mbase = real col mbase-8
        float zv[16];
#pragma unroll
        for (int q = 0; q < 4; ++q) {
            const float4 v = *reinterpret_cast<const float4*>(zr + (q << 2));
            zv[4 * q] = v.x; zv[4 * q + 1] = v.y; zv[4 * q + 2] = v.z; zv[4 * q + 3] = v.w;
        }
        float yv[16];
#pragma unroll
        for (int e = 0; e < 8; ++e) {        // m = mbase+e -> w = 2m, 2m+1
            float a0 = 0.0f, a1 = 0.0f;
#pragma unroll
            for (int tt = 0; tt < 6; ++tt) {
                const float zz = zv[8 + e - tt];
                a0 += fu[2 * tt]     * zz;
                a1 += fu[2 * tt + 1] * zz;
            }
            a0 += bv; a1 += bv;
            a0 = (a0 >= 0.0f ? a0 : SLOPE * a0) * GAIN;
            a1 = (a1 >= 0.0f ? a1 : SLOPE * a1) * GAIN;
            yv[2 * e] = a0; yv[2 * e + 1] = a1;
        }
        float* yr = yb + il * YSTRIDE + (mbase << 1);
#pragma unroll
        for (int q = 0; q < 4; ++q)
            *reinterpret_cast<float4*>(yr + (q << 2)) =
                make_float4(yv[4 * q], yv[4 * q + 1], yv[4 * q + 2], yv[4 * q + 3]);
    }
    __syncthreads();

    // ---- D: down-H -> wb[32][140].  Row padded to 40 tasks so 8-lane groups
    //      never straddle og boundaries; 16B lane-stride within row: clean. ----
    for (int task = t; task < 8 * 40; task += NT) {          // 320 (5/40 idle)
        const int og = task / 40;                            // 0..7
        const int cidx = task - og * 40;                     // 0..39
        if (cidx < 35) {
            const int col4 = cidx << 2;                      // 0..136
            const float* yr = yb + (og << 3) * YSTRIDE + col4;   // y rows 8og..8og+17
            float acc[4][4] = {{0,0,0,0},{0,0,0,0},{0,0,0,0},{0,0,0,0}};
#pragma unroll
            for (int r = 0; r < 18; ++r) {
                const float4 v = *reinterpret_cast<const float4*>(yr + r * YSTRIDE);
#pragma unroll
                for (int e = 0; e < 4; ++e) {
                    if (r >= 2 * e && r <= 2 * e + 11) {     // compile-time per (r,e)
                        const float w = fd[11 - r + 2 * e];
                        acc[e][0] += w * v.x; acc[e][1] += w * v.y;
                        acc[e][2] += w * v.z; acc[e][3] += w * v.w;
                    }
                }
            }
            float* wr = wb + (og << 2) * WSTRIDE + col4;
#pragma unroll
            for (int e = 0; e < 4; ++e)
                *reinterpret_cast<float4*>(wr + e * WSTRIDE) =
                    make_float4(acc[e][0], acc[e][1], acc[e][2], acc[e][3]);
        }
    }
    __syncthreads();

    // ---- E: down-W -> out.  Task = (ow8, ol) with ol FAST-varying:
    //      lane-stride 140 floats = 48B mod 128 -> full rotation, clean. ----
    for (int task = t; task < 8 * 32; task += NT) {          // 256
        const int ow8 = task >> 5;                           // 0..7
        const int ol  = task & 31;                           // 0..31
        const float* wr = wb + ol * WSTRIDE + (ow8 << 4);
        float wv[28];
#pragma unroll
        for (int q = 0; q < 7; ++q) {
            const float4 v = *reinterpret_cast<const float4*>(wr + (q << 2));
            wv[4 * q] = v.x; wv[4 * q + 1] = v.y; wv[4 * q + 2] = v.z; wv[4 * q + 3] = v.w;
        }
        float rv[8];
#pragma unroll
        for (int e = 0; e < 8; ++e) {
            float a = 0.0f;
#pragma unroll
            for (int j = 0; j < 12; ++j) a += fd[j] * wv[2 * e + 11 - j];
            rv[e] = a;
        }
        float* orow = og + (o0 + ol) * 64 + (ow8 << 3);
        *reinterpret_cast<float4*>(orow)     = make_float4(rv[0], rv[1], rv[2], rv[3]);
        *reinterpret_cast<float4*>(orow + 4) = make_float4(rv[4], rv[5], rv[6], rv[7]);
    }
}

extern "C" void kernel_launch(void* const* d_in, const int* in_sizes, int n_in,
                              void* d_out, int out_size, void* d_ws, size_t ws_size,
                              hipStream_t stream) {
    const float* x    = (const float*)d_in[0];
    const float* bias = (const float*)d_in[1];
    const float* upf  = (const float*)d_in[2];
    const float* dnf  = (const float*)d_in[3];
    float* out = (float*)d_out;

    const int n_blocks = 32 * 128 * 2;   // two half-slices per (n,c)
    const size_t lds_bytes = (size_t)LDS_FLOATS * sizeof(float);
    hipLaunchKernelGGL(fused_upfirdn_lrelu, dim3(n_blocks), dim3(NT),
                       lds_bytes, stream, x, bias, upf, dnf, out);
}

// Round 5
// 73.719 us; speedup vs baseline: 1.3713x; 1.0336x over previous
//
#include <hip/hip_runtime.h>

// Fused upfirdn2d: up2(FIR12,H) -> up2(FIR12,W) -> +bias -> lrelu*sqrt2
//                  -> down2(FIR12,H) -> down2(FIR12,W)
// x: (32,128,64,64) f32.  Two half-slice blocks per (n,c).
// R5 restructure:
//  - downW and downH commute (both linear, after lrelu): do downW on y first
//    into tiny yw[74][64], then downH straight to global. Kills the wb buffer.
//  - upH reads x directly from global (slice is L1-resident) -> no x staging.
//  - every phase is a single pass (if t<N), task groups padded to multiples
//    of 8 so b128 lane-groups never straddle row boundaries (bank-clean).
//
// Index math:
//   z[i][c]  = sum_{j == i (mod 2)} (2*fu[j]) * x[(i-j)/2][c]
//   y[i][w]  = sum_{j == w (mod 2)} (2*fu[j]) * z[i][(w-j)/2]; lrelu(y+b)*g
//   yw[i][p] = sum_{j} fd[j] * y[i][2p+11-j]          (down-W first)
//   out[o][p]= sum_{j} fd[j] * yw[2o+11-j][p]         (down-H second)

#define NT 1024
#define SLOPE 0.2f
#define GAIN 1.41421356237309504880f

#define ZROWS 74
#define ZSTRIDE 84            // 336B = 80B mod 128 -> full rotation on row-walk
#define ZPAD 8                // local col p <-> real z col p-8 ; pads zeroed
#define YROWS 74
#define YSTRIDE 148           // 592B = 80B mod 128 -> full rotation on row-walk
#define YWSTRIDE 68           // 272B = 16B mod 128 -> full rotation on row-walk

#define ZB_OFF 0
#define YB_OFF (ZROWS * ZSTRIDE)              // 6216
#define YW_OFF 0                              // yw aliases zb (zb dead after C)
#define LDS_FLOATS (YB_OFF + YROWS * YSTRIDE) // 17168 floats = 68672 B -> 2 blk/CU

__global__ __launch_bounds__(NT, 8) void fused_upfirdn_lrelu(
    const float* __restrict__ x,
    const float* __restrict__ bias,
    const float* __restrict__ upf,
    const float* __restrict__ dnf,
    float* __restrict__ out)
{
    extern __shared__ float lds[];
    float* zb = lds + ZB_OFF;
    float* yb = lds + YB_OFF;
    float* yw = lds + YW_OFF;

    const int t = threadIdx.x;
    const int bid = blockIdx.x;
    const int s = bid >> 1;           // slice = n*128 + c
    const int o0 = (bid & 1) << 5;    // 0 or 32
    const int c = s & 127;

    float fu[12], fd[12];
#pragma unroll
    for (int j = 0; j < 12; ++j) { fu[j] = 2.0f * upf[j]; fd[j] = dnf[j]; }
    const float bv = bias[c];

    const float* xg = x + (size_t)s * 4096;
    float* outg = out + (size_t)s * 4096;

    // ---- Phase 1: up-H from GLOBAL x -> z rows [0,74)  (t<304),
    //      plus z pad-column zeroing (t in [304,674)). ----
    if (t < 304) {
        const int k = t >> 4;                 // 0..18 ; z local rows 4k..4k+3
        const int c4 = (t & 15) << 2;
        const int rbase = o0 - 5 + 2 * k;     // x rows rbase..rbase+6
        float4 xv[7];
#pragma unroll
        for (int d = 0; d < 7; ++d) {
            const int r = rbase + d;
            if (r >= 0 && r <= 63)
                xv[d] = *reinterpret_cast<const float4*>(xg + r * 64 + c4);
            else
                xv[d] = make_float4(0.f, 0.f, 0.f, 0.f);
        }
        float a0[4] = {0,0,0,0}, a1[4] = {0,0,0,0}, b0[4] = {0,0,0,0}, b1[4] = {0,0,0,0};
#pragma unroll
        for (int d = 0; d < 6; ++d) {         // rows 4k,4k+1 use xv[0..5], tt = 5-d
            const float w0 = fu[2 * (5 - d)], w1 = fu[2 * (5 - d) + 1];
            a0[0] += w0 * xv[d].x; a0[1] += w0 * xv[d].y; a0[2] += w0 * xv[d].z; a0[3] += w0 * xv[d].w;
            a1[0] += w1 * xv[d].x; a1[1] += w1 * xv[d].y; a1[2] += w1 * xv[d].z; a1[3] += w1 * xv[d].w;
        }
#pragma unroll
        for (int d = 1; d < 7; ++d) {         // rows 4k+2,4k+3 use xv[1..6], tt = 6-d
            const float w0 = fu[2 * (6 - d)], w1 = fu[2 * (6 - d) + 1];
            b0[0] += w0 * xv[d].x; b0[1] += w0 * xv[d].y; b0[2] += w0 * xv[d].z; b0[3] += w0 * xv[d].w;
            b1[0] += w1 * xv[d].x; b1[1] += w1 * xv[d].y; b1[2] += w1 * xv[d].z; b1[3] += w1 * xv[d].w;
        }
        float* zr = zb + (4 * k) * ZSTRIDE + ZPAD + c4;
        *reinterpret_cast<float4*>(zr)               = make_float4(a0[0], a0[1], a0[2], a0[3]);
        *reinterpret_cast<float4*>(zr + ZSTRIDE)     = make_float4(a1[0], a1[1], a1[2], a1[3]);
        if (k < 18) {
            *reinterpret_cast<float4*>(zr + 2 * ZSTRIDE) = make_float4(b0[0], b0[1], b0[2], b0[3]);
            *reinterpret_cast<float4*>(zr + 3 * ZSTRIDE) = make_float4(b1[0], b1[1], b1[2], b1[3]);
        }
    } else if (t < 674) {
        const int pt = t - 304;               // zero cols [0,8) and [72,84)
        const int rl = pt / 5;
        const int p = pt - rl * 5;
        const int col = (p < 2) ? (p << 2) : (72 + ((p - 2) << 2));
        *reinterpret_cast<float4*>(zb + rl * ZSTRIDE + col) = make_float4(0.f, 0.f, 0.f, 0.f);
    }
    __syncthreads();

    // ---- Phase 2: up-W + bias + lrelu -> y[74][148].  t<720, 80 tasks per m8
    //      (il fast-varying, padded to 80 so lane-groups never straddle). ----
    if (t < 720) {
        const int m8 = t / 80;                // 0..8 ; m = 8*m8 .. 8*m8+7
        const int il = t - m8 * 80;
        if (il < YROWS) {
            const int mbase = m8 << 3;
            const float* zr = zb + il * ZSTRIDE + mbase;   // local col = real col + 8
            float zv[16];
#pragma unroll
            for (int q = 0; q < 4; ++q) {
                const float4 v = *reinterpret_cast<const float4*>(zr + (q << 2));
                zv[4 * q] = v.x; zv[4 * q + 1] = v.y; zv[4 * q + 2] = v.z; zv[4 * q + 3] = v.w;
            }
            float yv[16];
#pragma unroll
            for (int e = 0; e < 8; ++e) {     // m = mbase+e -> w = 2m, 2m+1
                float a0 = 0.0f, a1 = 0.0f;
#pragma unroll
                for (int tt = 0; tt < 6; ++tt) {
                    const float zz = zv[8 + e - tt];
                    a0 += fu[2 * tt]     * zz;
                    a1 += fu[2 * tt + 1] * zz;
                }
                a0 += bv; a1 += bv;
                a0 = (a0 >= 0.0f ? a0 : SLOPE * a0) * GAIN;
                a1 = (a1 >= 0.0f ? a1 : SLOPE * a1) * GAIN;
                yv[2 * e] = a0; yv[2 * e + 1] = a1;
            }
            float* yr = yb + il * YSTRIDE + (mbase << 1);
#pragma unroll
            for (int q = 0; q < 4; ++q)
                *reinterpret_cast<float4*>(yr + (q << 2)) =
                    make_float4(yv[4 * q], yv[4 * q + 1], yv[4 * q + 2], yv[4 * q + 3]);
        }
    }
    __syncthreads();

    // ---- Phase 3: down-W on y -> yw[74][64] (aliases zb).  t<640,
    //      8 outputs per task; il fast-varying, padded to 80 per colgroup. ----
    if (t < 640) {
        const int cg = t / 80;                // 0..7 ; outputs p = 8cg..8cg+7
        const int il = t - cg * 80;
        if (il < YROWS) {
            const float* yr = yb + il * YSTRIDE + (cg << 4);   // y cols 16cg..16cg+27
            float w[28];
#pragma unroll
            for (int q = 0; q < 7; ++q) {
                const float4 v = *reinterpret_cast<const float4*>(yr + (q << 2));
                w[4 * q] = v.x; w[4 * q + 1] = v.y; w[4 * q + 2] = v.z; w[4 * q + 3] = v.w;
            }
            float rv[8];
#pragma unroll
            for (int e = 0; e < 8; ++e) {     // p = 8cg+e : y cols 2p .. 2p+11
                float a = 0.0f;
#pragma unroll
                for (int j = 0; j < 12; ++j) a += fd[j] * w[2 * e + 11 - j];
                rv[e] = a;
            }
            float* wr = yw + il * YWSTRIDE + (cg << 3);
            *reinterpret_cast<float4*>(wr)     = make_float4(rv[0], rv[1], rv[2], rv[3]);
            *reinterpret_cast<float4*>(wr + 4) = make_float4(rv[4], rv[5], rv[6], rv[7]);
        }
    }
    __syncthreads();

    // ---- Phase 4: down-H on yw -> GLOBAL out.  t<128: strip of 4 out rows
    //      x 4 cols from 18 yw rows; stores straight to HBM. ----
    if (t < 128) {
        const int eg = t >> 4;                // 0..7 ; out rows 4eg..4eg+3
        const int col4 = (t & 15) << 2;       // 0..60
        const float* wr = yw + (eg << 3) * YWSTRIDE + col4;    // yw rows 8eg..8eg+17
        float acc[4][4] = {{0,0,0,0},{0,0,0,0},{0,0,0,0},{0,0,0,0}};
#pragma unroll
        for (int r = 0; r < 18; ++r) {
            const float4 v = *reinterpret_cast<const float4*>(wr + r * YWSTRIDE);
#pragma unroll
            for (int e = 0; e < 4; ++e) {
                if (r >= 2 * e && r <= 2 * e + 11) {           // compile-time per (r,e)
                    const float ww = fd[11 - r + 2 * e];
                    acc[e][0] += ww * v.x; acc[e][1] += ww * v.y;
                    acc[e][2] += ww * v.z; acc[e][3] += ww * v.w;
                }
            }
        }
#pragma unroll
        for (int e = 0; e < 4; ++e)
            *reinterpret_cast<float4*>(outg + (o0 + (eg << 2) + e) * 64 + col4) =
                make_float4(acc[e][0], acc[e][1], acc[e][2], acc[e][3]);
    }
}

extern "C" void kernel_launch(void* const* d_in, const int* in_sizes, int n_in,
                              void* d_out, int out_size, void* d_ws, size_t ws_size,
                              hipStream_t stream) {
    const float* x    = (const float*)d_in[0];
    const float* bias = (const float*)d_in[1];
    const float* upf  = (const float*)d_in[2];
    const float* dnf  = (const float*)d_in[3];
    float* out = (float*)d_out;

    const int n_blocks = 32 * 128 * 2;   // two half-slices per (n,c)
    const size_t lds_bytes = (size_t)LDS_FLOATS * sizeof(float);
    hipLaunchKernelGGL(fused_upfirdn_lrelu, dim3(n_blocks), dim3(NT),
                       lds_bytes, stream, x, bias, upf, dnf, out);
}